// Round 2
// baseline (388.727 us; speedup 1.0000x reference)
//
#include <hip/hip_runtime.h>
#include <math.h>

#define B_    32
#define C_    384
#define RHO_  25
#define WP_   256
#define PIX_  4096
#define D_    768
#define HID_  40
#define CARTBLK 192
#define POLARBLK 2048
#define NROWS (B_*C_*RHO_)   // 307200

__device__ __forceinline__ float gelu_exact(float x) {
    return 0.5f * x * (1.f + erff(x * 0.70710678118654752f));
}

// ---------------- K1: per-(b,rho) bin row via LDS atomics + W1 transpose ----------------
__global__ __launch_bounds__(256) void prep_kernel(const float* __restrict__ grid,
        const float* __restrict__ W1_0, const float* __restrict__ W1s,
        float* __restrict__ bins, float* __restrict__ W1T) {
    __shared__ float lb[PIX_];
    int tid = threadIdx.x;
    if (blockIdx.x < B_ * RHO_) {
        for (int i = tid; i < PIX_ / 4; i += 256) ((float4*)lb)[i] = make_float4(0.f, 0.f, 0.f, 0.f);
        __syncthreads();
        int pt = blockIdx.x * WP_ + tid;                 // (b,rho) block owns its 256 points
        float2 g = ((const float2*)grid)[pt];
        float ix = (g.x + 1.f) * 32.f - 0.5f;
        float iy = (g.y + 1.f) * 32.f - 0.5f;
        float x0f = floorf(ix), y0f = floorf(iy);
        float fx = ix - x0f, fy = iy - y0f;
        int x0 = (int)x0f, y0 = (int)y0f;
        const float s = 1.f / 256.f;
        if ((unsigned)x0 < 64u) {
            if ((unsigned)y0 < 64u)       atomicAdd(&lb[y0 * 64 + x0],       (1.f - fx) * (1.f - fy) * s);
            if ((unsigned)(y0 + 1) < 64u) atomicAdd(&lb[(y0 + 1) * 64 + x0], (1.f - fx) * fy * s);
        }
        if ((unsigned)(x0 + 1) < 64u) {
            if ((unsigned)y0 < 64u)       atomicAdd(&lb[y0 * 64 + x0 + 1],       fx * (1.f - fy) * s);
            if ((unsigned)(y0 + 1) < 64u) atomicAdd(&lb[(y0 + 1) * 64 + x0 + 1], fx * fy * s);
        }
        __syncthreads();
        float4* dst = (float4*)(bins + (size_t)blockIdx.x * PIX_);
        for (int i = tid; i < PIX_ / 4; i += 256) dst[i] = ((float4*)lb)[i];
    } else {
        int i = blockIdx.x - B_ * RHO_;                  // head 0..24
        const float* src = (i == 0) ? W1_0 : (W1s + (size_t)(i - 1) * 769 * HID_);
        float* dst = W1T + (size_t)i * HID_ * D_;
        for (int idx = tid; idx < HID_ * D_; idx += 256) {
            int j = idx / D_, c = idx % D_;
            dst[idx] = src[c * HID_ + j];                // write coalesced, read L2-cached
        }
    }
}

// ---------------- K2: fused polar-mean + cart-GEMM (share HBM BW) ----------------
__global__ __launch_bounds__(256) void fused_main_kernel(const float* __restrict__ polar,
        const float* __restrict__ cart, const float* __restrict__ bins,
        float* __restrict__ fe) {
    __shared__ float smem[12800];                        // 51.2 KB
    int tid = threadIdx.x;
    if (blockIdx.x < CARTBLK) {
        // ---- cart half: fe_cart[b,c,rho] = sum_p bins[b,rho,p]*cart[b,c,p]; 64 ch/block, 2/thread
        float* ldsW = smem;                              // [25][128]
        float* ldsX = smem + 3200;                       // [64][132] padded
        int b = blockIdx.x / 6, c0 = (blockIdx.x % 6) * 64;
        int c = tid & 31, q = tid >> 5;                  // q in 0..7
        float acc[2][25];
        #pragma unroll
        for (int r = 0; r < 25; ++r) { acc[0][r] = 0.f; acc[1][r] = 0.f; }
        const float* binb  = bins + (size_t)b * RHO_ * PIX_;
        const float* cartb = cart + ((size_t)b * C_ + c0) * PIX_;
        for (int t = 0; t < 32; ++t) {
            int p0 = t * 128;
            for (int idx = tid; idx < 800; idx += 256) { // W tile 25x128
                int rho = idx >> 5, c4 = idx & 31;
                *(float4*)(ldsW + rho * 128 + c4 * 4) =
                    *(const float4*)(binb + (size_t)rho * PIX_ + p0 + c4 * 4);
            }
            for (int idx = tid; idx < 2048; idx += 256) { // X tile 64x128
                int row = idx >> 5, c4 = idx & 31;
                *(float4*)(ldsX + row * 132 + c4 * 4) =
                    *(const float4*)(cartb + (size_t)row * PIX_ + p0 + c4 * 4);
            }
            __syncthreads();
            #pragma unroll
            for (int k = 0; k < 4; ++k) {
                int m4 = 4 * (q + 8 * k);
                float4 xa = *(const float4*)(ldsX + c * 132 + m4);
                float4 xb = *(const float4*)(ldsX + (c + 32) * 132 + m4);
                #pragma unroll
                for (int r = 0; r < 25; ++r) {
                    float4 w = *(const float4*)(ldsW + r * 128 + m4);  // 2 addrs/wave -> broadcast
                    acc[0][r] += xa.x * w.x + xa.y * w.y + xa.z * w.z + xa.w * w.w;
                    acc[1][r] += xb.x * w.x + xb.y * w.y + xb.z * w.z + xb.w * w.w;
                }
            }
            __syncthreads();
        }
        #pragma unroll
        for (int r = 0; r < 25; ++r) {
            smem[tid * 50 + r]      = acc[0][r];
            smem[tid * 50 + 25 + r] = acc[1][r];
        }
        __syncthreads();
        for (int oi = tid; oi < 1600; oi += 256) {
            int cc = oi / 25, rho = oi % 25;
            float ssum = 0.f;
            #pragma unroll
            for (int qq = 0; qq < 8; ++qq)
                ssum += smem[((qq << 5) + (cc & 31)) * 50 + (cc >> 5) * 25 + rho];
            fe[((size_t)(rho * B_ + b)) * D_ + 384 + c0 + cc] = ssum;
        }
    } else {
        // ---- polar half: mean over width, wave per row, grid-strided with ILP-2
        int wid = (blockIdx.x - CARTBLK) * 4 + (tid >> 6);
        int lane = tid & 63;
        const int NW = POLARBLK * 4;                     // 8192 waves
        for (int r = wid; r < NROWS; r += 2 * NW) {
            float4 v0 = ((const float4*)(polar + (size_t)r * WP_))[lane];
            int r2 = r + NW;
            float4 v1 = make_float4(0.f, 0.f, 0.f, 0.f);
            if (r2 < NROWS) v1 = ((const float4*)(polar + (size_t)r2 * WP_))[lane];
            float sa = v0.x + v0.y + v0.z + v0.w;
            float sb = v1.x + v1.y + v1.z + v1.w;
            #pragma unroll
            for (int m = 32; m >= 1; m >>= 1) { sa += __shfl_xor(sa, m, 64); sb += __shfl_xor(sb, m, 64); }
            if (lane == 0) {
                int rho = r % RHO_, cch = (r / RHO_) % C_, bb = r / (RHO_ * C_);
                fe[((size_t)(rho * B_ + bb)) * D_ + cch] = sa * (1.f / 256.f);
                if (r2 < NROWS) {
                    int rho2 = r2 % RHO_, c2 = (r2 / RHO_) % C_, b2 = r2 / (RHO_ * C_);
                    fe[((size_t)(rho2 * B_ + b2)) * D_ + c2] = sb * (1.f / 256.f);
                }
            }
        }
    }
}

// ---------------- K3: G[i][b][j] = fe[i][b][:] @ W1 + b1 ; wave per (i,b), coalesced W1T ----------------
__global__ __launch_bounds__(256) void mlp_pre_kernel(const float* __restrict__ fe,
        const float* __restrict__ W1T, const float* __restrict__ b1_0,
        const float* __restrict__ b1s, float* __restrict__ G) {
    int lane = threadIdx.x & 63;
    int pair = blockIdx.x * 4 + (threadIdx.x >> 6);      // 0..799 = (i,b)
    int i = pair >> 5, b = pair & 31;
    const float4* f4p = (const float4*)(fe + (size_t)(i * B_ + b) * D_);
    float4 f0 = f4p[lane], f1 = f4p[lane + 64], f2 = f4p[lane + 128];
    #pragma unroll 2
    for (int j = 0; j < HID_; ++j) {
        const float4* w4p = (const float4*)(W1T + ((size_t)i * HID_ + j) * D_);
        float4 w0 = w4p[lane], w1 = w4p[lane + 64], w2 = w4p[lane + 128];
        float s = f0.x*w0.x + f0.y*w0.y + f0.z*w0.z + f0.w*w0.w
                + f1.x*w1.x + f1.y*w1.y + f1.z*w1.z + f1.w*w1.w
                + f2.x*w2.x + f2.y*w2.y + f2.z*w2.z + f2.w*w2.w;
        #pragma unroll
        for (int m = 32; m >= 1; m >>= 1) s += __shfl_xor(s, m, 64);
        if (lane == 0) {
            float bias = (i == 0) ? b1_0[j] : b1s[(i - 1) * HID_ + j];
            G[(size_t)(i * B_ + b) * HID_ + j] = s + bias;
        }
    }
}

// ---------------- K4: sequential heads, fully register-resident, wave-synchronous ----------------
__global__ __launch_bounds__(64) void mlp_seq_kernel(const float* __restrict__ G,
        const float* __restrict__ W1s, const float* __restrict__ W2_0,
        const float* __restrict__ b2_0, const float* __restrict__ W2s,
        const float* __restrict__ b2s, float* __restrict__ out) {
    int lane = threadIdx.x;
    int j2 = lane & 31, b = blockIdx.x * 2 + (lane >> 5);
    bool hi = (j2 < 8);
    float g1[25], g2[25], wl1[25], wl2[25], w2a[25], w2b[25], bsc[25];
    #pragma unroll
    for (int i = 0; i < 25; ++i) {
        g1[i] = G[(size_t)(i * B_ + b) * HID_ + j2];
        g2[i] = hi ? G[(size_t)(i * B_ + b) * HID_ + 32 + j2] : 0.f;
    }
    wl1[0] = 0.f; wl2[0] = 0.f;
    w2a[0] = W2_0[j2]; w2b[0] = hi ? W2_0[32 + j2] : 0.f; bsc[0] = b2_0[0];
    #pragma unroll
    for (int i = 1; i < 25; ++i) {
        size_t base = ((size_t)(i - 1) * 769 + 768) * HID_;   // recurrent row of W1
        wl1[i] = W1s[base + j2];
        wl2[i] = hi ? W1s[base + 32 + j2] : 0.f;
        w2a[i] = W2s[(i - 1) * HID_ + j2];
        w2b[i] = hi ? W2s[(i - 1) * HID_ + 32 + j2] : 0.f;
        bsc[i] = b2s[i - 1];
    }
    float op = 0.f;
    #pragma unroll
    for (int i = 0; i < 25; ++i) {
        float x1 = g1[i] + op * wl1[i];
        float x2 = g2[i] + op * wl2[i];
        float p = gelu_exact(x1) * w2a[i] + gelu_exact(x2) * w2b[i];
        #pragma unroll
        for (int m = 16; m >= 1; m >>= 1) p += __shfl_xor(p, m, 64);   // stays within 32-lane group
        float o = p + bsc[i];
        op = o;
        if (j2 == 0) out[b * 25 + i] = fminf(fmaxf(o, 0.f), 3.14159265358979323846f);
    }
}

extern "C" void kernel_launch(void* const* d_in, const int* in_sizes, int n_in,
                              void* d_out, int out_size, void* d_ws, size_t ws_size,
                              hipStream_t stream) {
    const float* polar = (const float*)d_in[0];
    const float* cart  = (const float*)d_in[1];
    const float* grid  = (const float*)d_in[2];
    const float* W1_0  = (const float*)d_in[3];
    const float* b1_0  = (const float*)d_in[4];
    const float* W2_0  = (const float*)d_in[5];
    const float* b2_0  = (const float*)d_in[6];
    const float* W1s   = (const float*)d_in[7];
    const float* b1s   = (const float*)d_in[8];
    const float* W2s   = (const float*)d_in[9];
    const float* b2s   = (const float*)d_in[10];
    float* out = (float*)d_out;

    // ws layout (floats): bins[32*25*4096] | fe[25*32*768] | G[25*32*40] | W1T[25*40*768]
    float* bins = (float*)d_ws;
    float* fe   = bins + (size_t)B_ * RHO_ * PIX_;
    float* G    = fe + (size_t)RHO_ * B_ * D_;
    float* W1T  = G + (size_t)RHO_ * B_ * HID_;

    prep_kernel<<<B_ * RHO_ + 25, 256, 0, stream>>>(grid, W1_0, W1s, bins, W1T);
    fused_main_kernel<<<CARTBLK + POLARBLK, 256, 0, stream>>>(polar, cart, bins, fe);
    mlp_pre_kernel<<<(RHO_ * B_) / 4, 256, 0, stream>>>(fe, W1T, b1_0, b1s, G);
    mlp_seq_kernel<<<B_ / 2, 64, 0, stream>>>(G, W1s, W2_0, b2_0, W2s, b2s, out);
}